// Round 10
// baseline (796.916 us; speedup 1.0000x reference)
//
#include <hip/hip_runtime.h>
#include <stdint.h>
#include <math.h>

// ---------------------------------------------------------------------------
// Encoder (B=2,S=2048,D=512,H=8,dk=64,DFF=2048,L=4), fp32 in/out.
// r6 best-measured build (508 us) + attn occupancy bound 4->6 (25.3 KB LDS
// fits 6 blocks/CU; VGPR 60 <= 512/6=85 — free occupancy headroom).
// bf16 MFMA everywhere. Flash attention: static-max softmax, key-split x4,
// single-buffer staging, 32 q-rows/wave, XCD-locality swizzle, raw v_exp_f32,
// operand-swapped PV (O^T). GEMMs: 128x128, BK=32 dbuf staging for BOTH
// operands (direct-global B measured -86us worse, r9), 1 barrier/K-step.
// Split combines fused into the LayerNorm kernels.
// ---------------------------------------------------------------------------

typedef __bf16 bf16_t;
typedef bf16_t bf16x8 __attribute__((ext_vector_type(8)));
typedef bf16_t bf16x4v __attribute__((ext_vector_type(4)));
typedef float  f32x4  __attribute__((ext_vector_type(4)));

__device__ __forceinline__ f32x4 mfma16(bf16x8 a, bf16x8 b, f32x4 c) {
    return __builtin_amdgcn_mfma_f32_16x16x32_bf16(a, b, c, 0, 0, 0);
}

// async global->LDS, 16B/lane; LDS dest = wave-uniform base + lane*16
__device__ __forceinline__ void cp16(const void* g, const void* l) {
    auto gp = reinterpret_cast<const __attribute__((address_space(1))) char*>(
        reinterpret_cast<uintptr_t>(g));
    auto lp = reinterpret_cast<__attribute__((address_space(3))) char*>(
        static_cast<uint32_t>(reinterpret_cast<uintptr_t>(l)));
    __builtin_amdgcn_global_load_lds((const __attribute__((address_space(1))) void*)gp,
                                     (__attribute__((address_space(3))) void*)lp,
                                     16, 0, 0);
}

// ---------------------------------------------------------------------------
// Weight transpose+convert fp32 [K][N] -> bf16 [N][K]
// ---------------------------------------------------------------------------
__global__ void wconv_kernel(const float* __restrict__ Wq, const float* __restrict__ Wk,
                             const float* __restrict__ Wv, const float* __restrict__ W1,
                             const float* __restrict__ W2,
                             bf16_t* __restrict__ oQKV, bf16_t* __restrict__ oW1,
                             bf16_t* __restrict__ oW2)
{
    const int l = blockIdx.y;
    int t = blockIdx.x;
    const float* in; bf16_t* out; int Kd, Nd, tt;
    if (t < 192) {
        int m = t / 64; tt = t % 64; Kd = 512; Nd = 512;
        in  = (m == 0 ? Wq : m == 1 ? Wk : Wv) + (size_t)l * 512 * 512;
        out = oQKV + (size_t)l * 1536 * 512 + (size_t)m * 512 * 512;
    } else if (t < 448) {
        tt = t - 192; Kd = 512; Nd = 2048;
        in  = W1 + (size_t)l * 512 * 2048;
        out = oW1 + (size_t)l * 2048 * 512;
    } else {
        tt = t - 448; Kd = 2048; Nd = 512;
        in  = W2 + (size_t)l * 2048 * 512;
        out = oW2 + (size_t)l * 512 * 2048;
    }
    const int ntx = Nd >> 6;
    const int bk = (tt / ntx) * 64, bn = (tt % ntx) * 64;
    __shared__ float tile[64][65];
    const int tid = threadIdx.x;
    #pragma unroll
    for (int i = 0; i < 16; ++i) {
        int idx = i * 256 + tid; int r = idx >> 6, c = idx & 63;
        tile[r][c] = in[(size_t)(bk + r) * Nd + bn + c];
    }
    __syncthreads();
    #pragma unroll
    for (int i = 0; i < 4; ++i) {
        int idx = i * 256 + tid; int n = idx >> 4, kc = (idx & 15) * 4;
        bf16x4v o;
        o[0] = (bf16_t)tile[kc + 0][n];
        o[1] = (bf16_t)tile[kc + 1][n];
        o[2] = (bf16_t)tile[kc + 2][n];
        o[3] = (bf16_t)tile[kc + 3][n];
        *(bf16x4v*)&out[(size_t)(bn + n) * Kd + bk + kc] = o;
    }
}

__global__ void f2b_kernel(const float* __restrict__ in, bf16_t* __restrict__ out, int n)
{
    int i = (blockIdx.x * 256 + threadIdx.x) * 8;
    if (i >= n) return;
    float4 a = *(const float4*)(in + i);
    float4 b = *(const float4*)(in + i + 4);
    bf16x8 o;
    o[0] = (bf16_t)a.x; o[1] = (bf16_t)a.y; o[2] = (bf16_t)a.z; o[3] = (bf16_t)a.w;
    o[4] = (bf16_t)b.x; o[5] = (bf16_t)b.y; o[6] = (bf16_t)b.z; o[7] = (bf16_t)b.w;
    *(bf16x8*)(out + i) = o;
}

// ---------------------------------------------------------------------------
// GEMM: C = act(A[M,lda] @ Wt[N,lda]^T + bias), 128x128 tile, BK=32,
// double-buffered cp16 staging (A and B), ONE barrier per K-step.
// MODE 1: bf16 out [M,N], bias+optional RELU        (FFN1)
// MODE 2: fused QKV, N=1536: Q bf16 [M,512] PRE-SCALED by 0.125*log2(e);
//         K bf16; V bf16 [b,h,d,s]
// MODE 3: bf16 out at o0 + z*M*N, no bias           (FFN2 split-K partials)
// ---------------------------------------------------------------------------
template<int MODE, bool RELU>
__global__ __launch_bounds__(256, 4) void gemm_kernel(
    const bf16_t* __restrict__ A, const bf16_t* __restrict__ Wt,
    const float* __restrict__ b0, const float* __restrict__ b1, const float* __restrict__ b2,
    void* __restrict__ o0, void* __restrict__ o1, void* __restrict__ o2,
    int N, int lda, int klen)
{
    __shared__ __align__(16) bf16_t lA[2][128 * 32];
    __shared__ __align__(16) bf16_t lB[2][128 * 32];
    const int tid = threadIdx.x;
    const int lane = tid & 63, w = tid >> 6;
    const int wm = w >> 1, wn = w & 1;
    const int l15 = lane & 15, quad = lane >> 4;
    const int row0 = blockIdx.y * 128, col0 = blockIdx.x * 128;
    const int kst = blockIdx.z * klen, kend = kst + klen;
    const int wbase = (tid & 192) * 16;

    f32x4 acc[4][4] = {};
    const char* Ab = (const char*)A;
    const char* Bb = (const char*)Wt;

    auto stage = [&](int k0, int buf) {
        #pragma unroll
        for (int p = 0; p < 2; ++p) {
            int o = (p * 256 + tid) * 16;
            int r = o >> 6, cb = o & 63;
            cp16(Ab + ((size_t)(row0 + r) * lda + k0) * 2 + cb, (char*)lA[buf] + p * 4096 + wbase);
            cp16(Bb + ((size_t)(col0 + r) * lda + k0) * 2 + cb, (char*)lB[buf] + p * 4096 + wbase);
        }
    };

    stage(kst, 0);
    int it = 0;
    for (int k0 = kst; k0 < kend; k0 += 32, ++it) {
        __syncthreads();                       // drains prev stage (had compute to land)
        if (k0 + 32 < kend) stage(k0 + 32, (it + 1) & 1);
        const bf16_t* cA = lA[it & 1];
        const bf16_t* cB = lB[it & 1];
        bf16x8 af[4], bv_[4];
        #pragma unroll
        for (int i = 0; i < 4; ++i)
            af[i] = *(const bf16x8*)&cA[(wm * 64 + i * 16 + l15) * 32 + quad * 8];
        #pragma unroll
        for (int i = 0; i < 4; ++i)
            bv_[i] = *(const bf16x8*)&cB[(wn * 64 + i * 16 + l15) * 32 + quad * 8];
        #pragma unroll
        for (int mi = 0; mi < 4; ++mi)
            #pragma unroll
            for (int ni = 0; ni < 4; ++ni)
                acc[mi][ni] = mfma16(af[mi], bv_[ni], acc[mi][ni]);
    }

    #pragma unroll
    for (int mi = 0; mi < 4; ++mi) {
        const int rowb = row0 + wm * 64 + mi * 16 + quad * 4;
        #pragma unroll
        for (int ni = 0; ni < 4; ++ni) {
            const int col = col0 + wn * 64 + ni * 16 + l15;
            if (MODE == 1) {
                const float bias = b0[col];
                #pragma unroll
                for (int r = 0; r < 4; ++r) {
                    float v = acc[mi][ni][r] + bias;
                    if (RELU) v = fmaxf(v, 0.f);
                    ((bf16_t*)o0)[(size_t)(rowb + r) * N + col] = (bf16_t)v;
                }
            } else if (MODE == 3) {
                bf16_t* op = (bf16_t*)o0 + (size_t)blockIdx.z * 4096 * 512;
                #pragma unroll
                for (int r = 0; r < 4; ++r)
                    op[(size_t)(rowb + r) * N + col] = (bf16_t)acc[mi][ni][r];
            } else { // MODE 2
                if (col < 512) {
                    const float bias = b0[col];
                    #pragma unroll
                    for (int r = 0; r < 4; ++r)
                        ((bf16_t*)o0)[(size_t)(rowb + r) * 512 + col] =
                            (bf16_t)((acc[mi][ni][r] + bias) * 0.18033688f); // 0.125*log2(e)
                } else if (col < 1024) {
                    const int c = col - 512;
                    const float bias = b1[c];
                    #pragma unroll
                    for (int r = 0; r < 4; ++r)
                        ((bf16_t*)o1)[(size_t)(rowb + r) * 512 + c] =
                            (bf16_t)(acc[mi][ni][r] + bias);
                } else {
                    const int cv = col - 1024;
                    const int hh = cv >> 6, d = cv & 63;
                    const float bias = b2[cv];
                    const int b_ = rowb >> 11, s = rowb & 2047;
                    bf16x4v pk;
                    #pragma unroll
                    for (int r = 0; r < 4; ++r)
                        pk[r] = (bf16_t)(acc[mi][ni][r] + bias);
                    *(bf16x4v*)&((bf16_t*)o2)[(size_t)((b_ * 8 + hh) * 64 + d) * 2048 + s] = pk;
                }
            }
        }
    }
}

// ---------------------------------------------------------------------------
// Flash attention, static-max softmax, key-split x4, single-buffer staging.
// grid=(64 = bh + 16*sp, 16 q-blocks). (bh+16sp)%8 = bh%8 -> XCD L2 head
// locality. 4 waves x 32 q-rows = 128 q-rows/block. LDS 25.3 KB ->
// __launch_bounds__(256,6): 6 blocks/CU (VGPR 60 <= 85 cap) — occupancy is
// the measured lever on this kernel (r2->r3, r5->r6 wins; r7 loss).
// Q pre-scaled by 0.125*log2e -> p = (s==0) ? 0 : exp2(s) [mask quirk],
// raw v_exp_f32. PV operand-swapped (O^T) -> packed b64 O-stores.
// Writes unnormalized O (bf16) + l per (row,head,split). Combine = sum in LN1.
// ---------------------------------------------------------------------------
__global__ __launch_bounds__(256, 6) void attn_kernel(
    const bf16_t* __restrict__ Q, const bf16_t* __restrict__ Kg,
    const bf16_t* __restrict__ Vt, bf16_t* __restrict__ Op,
    float* __restrict__ Lb)
{
    __shared__ __align__(16) bf16_t lK[2][64 * 32];   // [d-half][key][32 d]
    __shared__ __align__(16) bf16_t lV[2][64 * 32];   // [key-half][d][32 key]
    __shared__ __align__(16) bf16_t lP[4][1152];      // [wave][32 rows x stride 36]
    const int tid = threadIdx.x;
    const int lane = tid & 63, w = tid >> 6;
    const int l15 = lane & 15, quad = lane >> 4;
    const int bh = blockIdx.x & 15, sp = blockIdx.x >> 4;
    const int b = bh >> 3, h = bh & 7;
    const int q0 = blockIdx.y * 128;
    const int kbase = sp * 512;
    const int wbase = w * 1024;
    const int srow = tid >> 2, scb = (tid & 3) * 16;

    // Q fragments: 2 row-blocks x 2 d-halves, held for all tiles
    bf16x8 qf[2][2];
    #pragma unroll
    for (int mi = 0; mi < 2; ++mi)
        #pragma unroll
        for (int ks = 0; ks < 2; ++ks)
            qf[mi][ks] = *(const bf16x8*)&Q[(size_t)(b * 2048 + q0 + w * 32 + mi * 16 + l15) * 512
                                            + h * 64 + ks * 32 + quad * 8];

    f32x4 oaccT[2][4] = {};                   // O^T: lane -> q=l15, d=nd*16+quad*4+r
    float tsum[2][4] = {};                    // rows quad*4+r, partial over l15 cols

    for (int t = 0; t < 8; ++t) {
        const int k0 = kbase + t * 64;
        __syncthreads();
        #pragma unroll
        for (int ks = 0; ks < 2; ++ks)
            cp16((const char*)Kg + ((size_t)(b * 2048 + k0 + srow) * 512 + h * 64 + ks * 32) * 2 + scb,
                 (char*)lK[ks] + wbase);
        #pragma unroll
        for (int g = 0; g < 2; ++g)
            cp16((const char*)Vt + ((size_t)(bh * 64 + srow) * 2048 + k0 + g * 32) * 2 + scb,
                 (char*)lV[g] + wbase);
        __syncthreads();

        // S = Q @ K^T : rows quad*4+r (+16*mi), key cols ni*16+l15
        f32x4 sacc[2][4] = {};
        #pragma unroll
        for (int ni = 0; ni < 4; ++ni) {
            bf16x8 kf0 = *(const bf16x8*)&lK[0][(ni * 16 + l15) * 32 + quad * 8];
            bf16x8 kf1 = *(const bf16x8*)&lK[1][(ni * 16 + l15) * 32 + quad * 8];
            sacc[0][ni] = mfma16(qf[0][0], kf0, sacc[0][ni]);
            sacc[0][ni] = mfma16(qf[0][1], kf1, sacc[0][ni]);
            sacc[1][ni] = mfma16(qf[1][0], kf0, sacc[1][ni]);
            sacc[1][ni] = mfma16(qf[1][1], kf1, sacc[1][ni]);
        }

        // mask quirk + exp2 (raw) + local sum
        #pragma unroll
        for (int mi = 0; mi < 2; ++mi)
            #pragma unroll
            for (int ni = 0; ni < 4; ++ni)
                #pragma unroll
                for (int r = 0; r < 4; ++r) {
                    float s = sacc[mi][ni][r];
                    float p_ = (s == 0.f) ? 0.f : __builtin_amdgcn_exp2f(s);
                    sacc[mi][ni][r] = p_;
                    tsum[mi][r] += p_;
                }

        // P through wave-private LDS (stride 36), then O^T += V^T P^T
        #pragma unroll
        for (int kc = 0; kc < 2; ++kc) {
            #pragma unroll
            for (int mi = 0; mi < 2; ++mi)
                #pragma unroll
                for (int nn = 0; nn < 2; ++nn) {
                    const int ni = kc * 2 + nn;
                    #pragma unroll
                    for (int r = 0; r < 4; ++r)
                        lP[w][(mi * 16 + quad * 4 + r) * 36 + nn * 16 + l15] =
                            (bf16_t)sacc[mi][ni][r];
                }
            bf16x8 pf[2];
            #pragma unroll
            for (int mi = 0; mi < 2; ++mi) {
                bf16x4v p0 = *(const bf16x4v*)&lP[w][(mi * 16 + l15) * 36 + quad * 8];
                bf16x4v p1 = *(const bf16x4v*)&lP[w][(mi * 16 + l15) * 36 + quad * 8 + 4];
                #pragma unroll
                for (int j = 0; j < 4; ++j) { pf[mi][j] = p0[j]; pf[mi][4 + j] = p1[j]; }
            }
            #pragma unroll
            for (int nd = 0; nd < 4; ++nd) {
                bf16x8 vf = *(const bf16x8*)&lV[kc][(nd * 16 + l15) * 32 + quad * 8];
                oaccT[0][nd] = mfma16(vf, pf[0], oaccT[0][nd]);   // operand swap -> O^T
                oaccT[1][nd] = mfma16(vf, pf[1], oaccT[1][nd]);
            }
        }
    }

    // row-sum reduction across the 16 key-col lanes (once per block)
    #pragma unroll
    for (int mi = 0; mi < 2; ++mi)
        #pragma unroll
        for (int r = 0; r < 4; ++r) {
            float s_ = tsum[mi][r];
            s_ += __shfl_xor(s_, 1);
            s_ += __shfl_xor(s_, 2);
            s_ += __shfl_xor(s_, 4);
            s_ += __shfl_xor(s_, 8);
            tsum[mi][r] = s_;
        }

    // epilogue: unnormalized O (packed b64 stores) + l
    bf16_t* op = Op + (size_t)sp * 4096 * 512;
    #pragma unroll
    for (int mi = 0; mi < 2; ++mi) {
        const int row = b * 2048 + q0 + w * 32 + mi * 16 + l15;
        #pragma unroll
        for (int nd = 0; nd < 4; ++nd) {
            bf16x4v pk;
            #pragma unroll
            for (int r = 0; r < 4; ++r) pk[r] = (bf16_t)oaccT[mi][nd][r];
            *(bf16x4v*)&op[(size_t)row * 512 + h * 64 + nd * 16 + quad * 4] = pk;
        }
        if (l15 == 0) {
            #pragma unroll
            for (int r = 0; r < 4; ++r) {
                int rr = b * 2048 + q0 + w * 32 + mi * 16 + quad * 4 + r;
                Lb[((size_t)rr * 8 + h) * 4 + sp] = tsum[mi][r];
            }
        }
    }
}

// ---------------------------------------------------------------------------
// LN1: sum 4 attention partials + residual, LayerNorm. 1 wave/row,
// lane owns 8 consecutive columns (all loads/stores 16B coalesced).
// ---------------------------------------------------------------------------
__global__ void lnadd_c(const bf16_t* __restrict__ Op, const float* __restrict__ Lb,
                        const float* __restrict__ hin,
                        const float* __restrict__ g, const float* __restrict__ be,
                        float* __restrict__ Yf, bf16_t* __restrict__ Yb)
{
    const int row = blockIdx.x * 4 + (threadIdx.x >> 6);
    const int lane = threadIdx.x & 63;
    const int c0 = lane * 8;
    const int head = lane >> 3;
    const float4 l4 = *(const float4*)&Lb[((size_t)row * 8 + head) * 4];
    const float linv = 1.f / (l4.x + l4.y + l4.z + l4.w);
    const size_t idx = (size_t)row * 512 + c0;
    bf16x8 o0 = *(const bf16x8*)&Op[idx];
    bf16x8 o1 = *(const bf16x8*)&Op[idx + 2097152];
    bf16x8 o2 = *(const bf16x8*)&Op[idx + 2 * 2097152];
    bf16x8 o3 = *(const bf16x8*)&Op[idx + 3 * 2097152];
    float4 h0 = *(const float4*)&hin[idx];
    float4 h1 = *(const float4*)&hin[idx + 4];
    const float hr[8] = {h0.x, h0.y, h0.z, h0.w, h1.x, h1.y, h1.z, h1.w};
    float v[8]; float s = 0.f;
    #pragma unroll
    for (int j = 0; j < 8; ++j) {
        v[j] = ((float)o0[j] + (float)o1[j] + (float)o2[j] + (float)o3[j]) * linv + hr[j];
        s += v[j];
    }
    #pragma unroll
    for (int off = 32; off >= 1; off >>= 1) s += __shfl_xor(s, off);
    const float mean = s * (1.f / 512.f);
    float vs = 0.f;
    #pragma unroll
    for (int j = 0; j < 8; ++j) { float d = v[j] - mean; vs += d * d; }
    #pragma unroll
    for (int off = 32; off >= 1; off >>= 1) vs += __shfl_xor(vs, off);
    const float inv = rsqrtf(vs * (1.f / 512.f) + 1e-5f);
    float4 g0 = *(const float4*)&g[c0], g1 = *(const float4*)&g[c0 + 4];
    float4 b0 = *(const float4*)&be[c0], b1 = *(const float4*)&be[c0 + 4];
    const float gg[8] = {g0.x, g0.y, g0.z, g0.w, g1.x, g1.y, g1.z, g1.w};
    const float bb[8] = {b0.x, b0.y, b0.z, b0.w, b1.x, b1.y, b1.z, b1.w};
    float y[8]; bf16x8 yb;
    #pragma unroll
    for (int j = 0; j < 8; ++j) {
        y[j] = (v[j] - mean) * inv * gg[j] + bb[j];
        yb[j] = (bf16_t)y[j];
    }
    *(float4*)&Yf[idx]     = make_float4(y[0], y[1], y[2], y[3]);
    *(float4*)&Yf[idx + 4] = make_float4(y[4], y[5], y[6], y[7]);
    *(bf16x8*)&Yb[idx] = yb;
}

// ---------------------------------------------------------------------------
// LN2: sum 4 FFN2 split-K partials + bias + residual, LayerNorm.
// ---------------------------------------------------------------------------
__global__ void lnadd_f(const bf16_t* __restrict__ G, const float* __restrict__ bias,
                        const float* __restrict__ hres, const float* __restrict__ g,
                        const float* __restrict__ be,
                        float* __restrict__ Yf, bf16_t* __restrict__ Yb)
{
    const int row = blockIdx.x * 4 + (threadIdx.x >> 6);
    const int lane = threadIdx.x & 63;
    const int c0 = lane * 8;
    const size_t idx = (size_t)row * 512 + c0;
    bf16x8 o0 = *(const bf16x8*)&G[idx];
    bf16x8 o1 = *(const bf16x8*)&G[idx + 2097152];
    bf16x8 o2 = *(const bf16x8*)&G[idx + 2 * 2097152];
    bf16x8 o3 = *(const bf16x8*)&G[idx + 3 * 2097152];
    float4 h0 = *(const float4*)&hres[idx];
    float4 h1 = *(const float4*)&hres[idx + 4];
    float4 bi0 = *(const float4*)&bias[c0], bi1 = *(const float4*)&bias[c0 + 4];
    const float hr[8] = {h0.x, h0.y, h0.z, h0.w, h1.x, h1.y, h1.z, h1.w};
    const float bs[8] = {bi0.x, bi0.y, bi0.z, bi0.w, bi1.x, bi1.y, bi1.z, bi1.w};
    float v[8]; float s = 0.f;
    #pragma unroll
    for (int j = 0; j < 8; ++j) {
        v[j] = (float)o0[j] + (float)o1[j] + (float)o2[j] + (float)o3[j] + bs[j] + hr[j];
        s += v[j];
    }
    #pragma unroll
    for (int off = 32; off >= 1; off >>= 1) s += __shfl_xor(s, off);
    const float mean = s * (1.f / 512.f);
    float vs = 0.f;
    #pragma unroll
    for (int j = 0; j < 8; ++j) { float d = v[j] - mean; vs += d * d; }
    #pragma unroll
    for (int off = 32; off >= 1; off >>= 1) vs += __shfl_xor(vs, off);
    const float inv = rsqrtf(vs * (1.f / 512.f) + 1e-5f);
    float4 g0 = *(const float4*)&g[c0], g1 = *(const float4*)&g[c0 + 4];
    float4 b0 = *(const float4*)&be[c0], b1 = *(const float4*)&be[c0 + 4];
    const float gg[8] = {g0.x, g0.y, g0.z, g0.w, g1.x, g1.y, g1.z, g1.w};
    const float bb[8] = {b0.x, b0.y, b0.z, b0.w, b1.x, b1.y, b1.z, b1.w};
    float y[8]; bf16x8 yb;
    #pragma unroll
    for (int j = 0; j < 8; ++j) {
        y[j] = (v[j] - mean) * inv * gg[j] + bb[j];
        yb[j] = (bf16_t)y[j];
    }
    *(float4*)&Yf[idx]     = make_float4(y[0], y[1], y[2], y[3]);
    *(float4*)&Yf[idx + 4] = make_float4(y[4], y[5], y[6], y[7]);
    *(bf16x8*)&Yb[idx] = yb;
}

// ---------------------------------------------------------------------------
extern "C" void kernel_launch(void* const* d_in, const int* in_sizes, int n_in,
                              void* d_out, int out_size, void* d_ws, size_t ws_size,
                              hipStream_t stream)
{
    const float* x   = (const float*)d_in[0];
    const float* Wq  = (const float*)d_in[1];
    const float* bq  = (const float*)d_in[2];
    const float* Wk  = (const float*)d_in[3];
    const float* bk  = (const float*)d_in[4];
    const float* Wv  = (const float*)d_in[5];
    const float* bv  = (const float*)d_in[6];
    const float* W1  = (const float*)d_in[7];
    const float* b1  = (const float*)d_in[8];
    const float* W2  = (const float*)d_in[9];
    const float* b2  = (const float*)d_in[10];
    const float* g1  = (const float*)d_in[11];
    const float* be1 = (const float*)d_in[12];
    const float* g2  = (const float*)d_in[13];
    const float* be2 = (const float*)d_in[14];

    char* p = (char*)d_ws;
    auto carve = [&](size_t bytes) { char* r = p; p += (bytes + 255) & ~(size_t)255; return r; };
    bf16_t* wQKV = (bf16_t*)carve(4UL * 1536 * 512 * 2);
    bf16_t* wW1t = (bf16_t*)carve(4UL * 2048 * 512 * 2);
    bf16_t* wW2t = (bf16_t*)carve(4UL * 512 * 2048 * 2);
    bf16_t* hbf  = (bf16_t*)carve(4096UL * 512 * 2);       // bf16 of current h
    bf16_t* h2b  = (bf16_t*)carve(4096UL * 512 * 2);       // bf16 of LN1 out
    bf16_t* Fb   = (bf16_t*)carve(4096UL * 2048 * 2);      // FFN1 out; Q/K/V alias
    bf16_t* R2   = (bf16_t*)carve(4UL * 4096 * 512 * 2);   // attn / FFN2 partials
    float*  Lbuf = (float*)carve(4096UL * 8 * 4 * 4);
    float*  h2f  = (float*)carve(4096UL * 512 * 4);        // LN1 out fp32
    float*  hf   = (float*)carve(4096UL * 512 * 4);        // h master fp32
    bf16_t* Qb  = Fb;
    bf16_t* Kb  = Fb + 4096UL * 512;
    bf16_t* Vtb = Fb + 2UL * 4096 * 512;                   // [b][h][64][2048]

    wconv_kernel<<<dim3(704, 4), 256, 0, stream>>>(Wq, Wk, Wv, W1, W2, wQKV, wW1t, wW2t);
    f2b_kernel<<<dim3(1024), 256, 0, stream>>>(x, hbf, 4096 * 512);

    const float* hin = x;
    for (int l = 0; l < 4; ++l) {
        gemm_kernel<2, false><<<dim3(12, 32, 1), 256, 0, stream>>>(
            hbf, wQKV + (size_t)l * 1536 * 512,
            bq + l * 512, bk + l * 512, bv + l * 512,
            Qb, Kb, Vtb, 1536, 512, 512);
        attn_kernel<<<dim3(64, 16), 256, 0, stream>>>(Qb, Kb, Vtb, R2, Lbuf);
        lnadd_c<<<dim3(1024), 256, 0, stream>>>(R2, Lbuf, hin,
                                                g1 + l * 512, be1 + l * 512, h2f, h2b);
        gemm_kernel<1, true><<<dim3(16, 32, 1), 256, 0, stream>>>(
            h2b, wW1t + (size_t)l * 2048 * 512,
            b1 + l * 2048, nullptr, nullptr,
            Fb, nullptr, nullptr, 2048, 512, 512);
        gemm_kernel<3, false><<<dim3(4, 32, 4), 256, 0, stream>>>(
            Fb, wW2t + (size_t)l * 512 * 2048,
            nullptr, nullptr, nullptr,
            R2, nullptr, nullptr, 512, 2048, 512);
        float* yout = (l == 3) ? (float*)d_out : hf;
        lnadd_f<<<dim3(1024), 256, 0, stream>>>(R2, b2 + l * 512, h2f,
                                                g2 + l * 512, be2 + l * 512, yout, hbf);
        hin = hf;
    }
    (void)in_sizes; (void)n_in; (void)out_size; (void)ws_size;
}

// Round 11
// 503.654 us; speedup vs baseline: 1.5823x; 1.5823x over previous
//
#include <hip/hip_runtime.h>
#include <stdint.h>
#include <math.h>

// ---------------------------------------------------------------------------
// Encoder (B=2,S=2048,D=512,H=8,dk=64,DFF=2048,L=4), fp32 in/out.
// r6 build — measured optimum (508 us) across rounds 1-10. All perturbations
// (dbuf attn staging, 64-row waves, key-split x8, TM=64 GEMM, direct-global B,
// launch_bounds 6) measured worse; launch_bounds(256,6) caused VGPR spills
// (206MB scratch reads/dispatch, r10). Keep (256,4) everywhere.
// bf16 MFMA; flash attention: static-max softmax, key-split x4, 32 q-rows
// per wave, single-buffer cp16 staging, XCD swizzle, raw v_exp_f32,
// operand-swapped PV (O^T). GEMMs: 128x128, BK=32 dbuf both operands,
// 1 barrier/K-step. Split combines fused into LayerNorm kernels.
// ---------------------------------------------------------------------------

typedef __bf16 bf16_t;
typedef bf16_t bf16x8 __attribute__((ext_vector_type(8)));
typedef bf16_t bf16x4v __attribute__((ext_vector_type(4)));
typedef float  f32x4  __attribute__((ext_vector_type(4)));

__device__ __forceinline__ f32x4 mfma16(bf16x8 a, bf16x8 b, f32x4 c) {
    return __builtin_amdgcn_mfma_f32_16x16x32_bf16(a, b, c, 0, 0, 0);
}

// async global->LDS, 16B/lane; LDS dest = wave-uniform base + lane*16
__device__ __forceinline__ void cp16(const void* g, const void* l) {
    auto gp = reinterpret_cast<const __attribute__((address_space(1))) char*>(
        reinterpret_cast<uintptr_t>(g));
    auto lp = reinterpret_cast<__attribute__((address_space(3))) char*>(
        static_cast<uint32_t>(reinterpret_cast<uintptr_t>(l)));
    __builtin_amdgcn_global_load_lds((const __attribute__((address_space(1))) void*)gp,
                                     (__attribute__((address_space(3))) void*)lp,
                                     16, 0, 0);
}

// ---------------------------------------------------------------------------
// Weight transpose+convert fp32 [K][N] -> bf16 [N][K]
// ---------------------------------------------------------------------------
__global__ void wconv_kernel(const float* __restrict__ Wq, const float* __restrict__ Wk,
                             const float* __restrict__ Wv, const float* __restrict__ W1,
                             const float* __restrict__ W2,
                             bf16_t* __restrict__ oQKV, bf16_t* __restrict__ oW1,
                             bf16_t* __restrict__ oW2)
{
    const int l = blockIdx.y;
    int t = blockIdx.x;
    const float* in; bf16_t* out; int Kd, Nd, tt;
    if (t < 192) {
        int m = t / 64; tt = t % 64; Kd = 512; Nd = 512;
        in  = (m == 0 ? Wq : m == 1 ? Wk : Wv) + (size_t)l * 512 * 512;
        out = oQKV + (size_t)l * 1536 * 512 + (size_t)m * 512 * 512;
    } else if (t < 448) {
        tt = t - 192; Kd = 512; Nd = 2048;
        in  = W1 + (size_t)l * 512 * 2048;
        out = oW1 + (size_t)l * 2048 * 512;
    } else {
        tt = t - 448; Kd = 2048; Nd = 512;
        in  = W2 + (size_t)l * 2048 * 512;
        out = oW2 + (size_t)l * 512 * 2048;
    }
    const int ntx = Nd >> 6;
    const int bk = (tt / ntx) * 64, bn = (tt % ntx) * 64;
    __shared__ float tile[64][65];
    const int tid = threadIdx.x;
    #pragma unroll
    for (int i = 0; i < 16; ++i) {
        int idx = i * 256 + tid; int r = idx >> 6, c = idx & 63;
        tile[r][c] = in[(size_t)(bk + r) * Nd + bn + c];
    }
    __syncthreads();
    #pragma unroll
    for (int i = 0; i < 4; ++i) {
        int idx = i * 256 + tid; int n = idx >> 4, kc = (idx & 15) * 4;
        bf16x4v o;
        o[0] = (bf16_t)tile[kc + 0][n];
        o[1] = (bf16_t)tile[kc + 1][n];
        o[2] = (bf16_t)tile[kc + 2][n];
        o[3] = (bf16_t)tile[kc + 3][n];
        *(bf16x4v*)&out[(size_t)(bn + n) * Kd + bk + kc] = o;
    }
}

__global__ void f2b_kernel(const float* __restrict__ in, bf16_t* __restrict__ out, int n)
{
    int i = (blockIdx.x * 256 + threadIdx.x) * 8;
    if (i >= n) return;
    float4 a = *(const float4*)(in + i);
    float4 b = *(const float4*)(in + i + 4);
    bf16x8 o;
    o[0] = (bf16_t)a.x; o[1] = (bf16_t)a.y; o[2] = (bf16_t)a.z; o[3] = (bf16_t)a.w;
    o[4] = (bf16_t)b.x; o[5] = (bf16_t)b.y; o[6] = (bf16_t)b.z; o[7] = (bf16_t)b.w;
    *(bf16x8*)(out + i) = o;
}

// ---------------------------------------------------------------------------
// GEMM: C = act(A[M,lda] @ Wt[N,lda]^T + bias), 128x128 tile, BK=32,
// double-buffered cp16 staging (A and B), ONE barrier per K-step.
// MODE 1: bf16 out [M,N], bias+optional RELU        (FFN1)
// MODE 2: fused QKV, N=1536: Q bf16 [M,512] PRE-SCALED by 0.125*log2(e);
//         K bf16; V bf16 [b,h,d,s]
// MODE 3: bf16 out at o0 + z*M*N, no bias           (FFN2 split-K partials)
// ---------------------------------------------------------------------------
template<int MODE, bool RELU>
__global__ __launch_bounds__(256, 4) void gemm_kernel(
    const bf16_t* __restrict__ A, const bf16_t* __restrict__ Wt,
    const float* __restrict__ b0, const float* __restrict__ b1, const float* __restrict__ b2,
    void* __restrict__ o0, void* __restrict__ o1, void* __restrict__ o2,
    int N, int lda, int klen)
{
    __shared__ __align__(16) bf16_t lA[2][128 * 32];
    __shared__ __align__(16) bf16_t lB[2][128 * 32];
    const int tid = threadIdx.x;
    const int lane = tid & 63, w = tid >> 6;
    const int wm = w >> 1, wn = w & 1;
    const int l15 = lane & 15, quad = lane >> 4;
    const int row0 = blockIdx.y * 128, col0 = blockIdx.x * 128;
    const int kst = blockIdx.z * klen, kend = kst + klen;
    const int wbase = (tid & 192) * 16;

    f32x4 acc[4][4] = {};
    const char* Ab = (const char*)A;
    const char* Bb = (const char*)Wt;

    auto stage = [&](int k0, int buf) {
        #pragma unroll
        for (int p = 0; p < 2; ++p) {
            int o = (p * 256 + tid) * 16;
            int r = o >> 6, cb = o & 63;
            cp16(Ab + ((size_t)(row0 + r) * lda + k0) * 2 + cb, (char*)lA[buf] + p * 4096 + wbase);
            cp16(Bb + ((size_t)(col0 + r) * lda + k0) * 2 + cb, (char*)lB[buf] + p * 4096 + wbase);
        }
    };

    stage(kst, 0);
    int it = 0;
    for (int k0 = kst; k0 < kend; k0 += 32, ++it) {
        __syncthreads();                       // drains prev stage (had compute to land)
        if (k0 + 32 < kend) stage(k0 + 32, (it + 1) & 1);
        const bf16_t* cA = lA[it & 1];
        const bf16_t* cB = lB[it & 1];
        bf16x8 af[4], bv_[4];
        #pragma unroll
        for (int i = 0; i < 4; ++i)
            af[i] = *(const bf16x8*)&cA[(wm * 64 + i * 16 + l15) * 32 + quad * 8];
        #pragma unroll
        for (int i = 0; i < 4; ++i)
            bv_[i] = *(const bf16x8*)&cB[(wn * 64 + i * 16 + l15) * 32 + quad * 8];
        #pragma unroll
        for (int mi = 0; mi < 4; ++mi)
            #pragma unroll
            for (int ni = 0; ni < 4; ++ni)
                acc[mi][ni] = mfma16(af[mi], bv_[ni], acc[mi][ni]);
    }

    #pragma unroll
    for (int mi = 0; mi < 4; ++mi) {
        const int rowb = row0 + wm * 64 + mi * 16 + quad * 4;
        #pragma unroll
        for (int ni = 0; ni < 4; ++ni) {
            const int col = col0 + wn * 64 + ni * 16 + l15;
            if (MODE == 1) {
                const float bias = b0[col];
                #pragma unroll
                for (int r = 0; r < 4; ++r) {
                    float v = acc[mi][ni][r] + bias;
                    if (RELU) v = fmaxf(v, 0.f);
                    ((bf16_t*)o0)[(size_t)(rowb + r) * N + col] = (bf16_t)v;
                }
            } else if (MODE == 3) {
                bf16_t* op = (bf16_t*)o0 + (size_t)blockIdx.z * 4096 * 512;
                #pragma unroll
                for (int r = 0; r < 4; ++r)
                    op[(size_t)(rowb + r) * N + col] = (bf16_t)acc[mi][ni][r];
            } else { // MODE 2
                if (col < 512) {
                    const float bias = b0[col];
                    #pragma unroll
                    for (int r = 0; r < 4; ++r)
                        ((bf16_t*)o0)[(size_t)(rowb + r) * 512 + col] =
                            (bf16_t)((acc[mi][ni][r] + bias) * 0.18033688f); // 0.125*log2(e)
                } else if (col < 1024) {
                    const int c = col - 512;
                    const float bias = b1[c];
                    #pragma unroll
                    for (int r = 0; r < 4; ++r)
                        ((bf16_t*)o1)[(size_t)(rowb + r) * 512 + c] =
                            (bf16_t)(acc[mi][ni][r] + bias);
                } else {
                    const int cv = col - 1024;
                    const int hh = cv >> 6, d = cv & 63;
                    const float bias = b2[cv];
                    const int b_ = rowb >> 11, s = rowb & 2047;
                    bf16x4v pk;
                    #pragma unroll
                    for (int r = 0; r < 4; ++r)
                        pk[r] = (bf16_t)(acc[mi][ni][r] + bias);
                    *(bf16x4v*)&((bf16_t*)o2)[(size_t)((b_ * 8 + hh) * 64 + d) * 2048 + s] = pk;
                }
            }
        }
    }
}

// ---------------------------------------------------------------------------
// Flash attention, static-max softmax, key-split x4, single-buffer staging.
// grid=(64 = bh + 16*sp, 16 q-blocks). (bh+16sp)%8 = bh%8 -> XCD L2 head
// locality. 4 waves x 32 q-rows = 128 q-rows/block. __launch_bounds__(256,4):
// VGPR ~60 fits; (256,6) measured -> spills (r10).
// Q pre-scaled by 0.125*log2e -> p = (s==0) ? 0 : exp2(s) [mask quirk],
// raw v_exp_f32. PV operand-swapped (O^T) -> packed b64 O-stores.
// Writes unnormalized O (bf16) + l per (row,head,split). Combine = sum in LN1.
// ---------------------------------------------------------------------------
__global__ __launch_bounds__(256, 4) void attn_kernel(
    const bf16_t* __restrict__ Q, const bf16_t* __restrict__ Kg,
    const bf16_t* __restrict__ Vt, bf16_t* __restrict__ Op,
    float* __restrict__ Lb)
{
    __shared__ __align__(16) bf16_t lK[2][64 * 32];   // [d-half][key][32 d]
    __shared__ __align__(16) bf16_t lV[2][64 * 32];   // [key-half][d][32 key]
    __shared__ __align__(16) bf16_t lP[4][1152];      // [wave][32 rows x stride 36]
    const int tid = threadIdx.x;
    const int lane = tid & 63, w = tid >> 6;
    const int l15 = lane & 15, quad = lane >> 4;
    const int bh = blockIdx.x & 15, sp = blockIdx.x >> 4;
    const int b = bh >> 3, h = bh & 7;
    const int q0 = blockIdx.y * 128;
    const int kbase = sp * 512;
    const int wbase = w * 1024;
    const int srow = tid >> 2, scb = (tid & 3) * 16;

    // Q fragments: 2 row-blocks x 2 d-halves, held for all tiles
    bf16x8 qf[2][2];
    #pragma unroll
    for (int mi = 0; mi < 2; ++mi)
        #pragma unroll
        for (int ks = 0; ks < 2; ++ks)
            qf[mi][ks] = *(const bf16x8*)&Q[(size_t)(b * 2048 + q0 + w * 32 + mi * 16 + l15) * 512
                                            + h * 64 + ks * 32 + quad * 8];

    f32x4 oaccT[2][4] = {};                   // O^T: lane -> q=l15, d=nd*16+quad*4+r
    float tsum[2][4] = {};                    // rows quad*4+r, partial over l15 cols

    for (int t = 0; t < 8; ++t) {
        const int k0 = kbase + t * 64;
        __syncthreads();
        #pragma unroll
        for (int ks = 0; ks < 2; ++ks)
            cp16((const char*)Kg + ((size_t)(b * 2048 + k0 + srow) * 512 + h * 64 + ks * 32) * 2 + scb,
                 (char*)lK[ks] + wbase);
        #pragma unroll
        for (int g = 0; g < 2; ++g)
            cp16((const char*)Vt + ((size_t)(bh * 64 + srow) * 2048 + k0 + g * 32) * 2 + scb,
                 (char*)lV[g] + wbase);
        __syncthreads();

        // S = Q @ K^T : rows quad*4+r (+16*mi), key cols ni*16+l15
        f32x4 sacc[2][4] = {};
        #pragma unroll
        for (int ni = 0; ni < 4; ++ni) {
            bf16x8 kf0 = *(const bf16x8*)&lK[0][(ni * 16 + l15) * 32 + quad * 8];
            bf16x8 kf1 = *(const bf16x8*)&lK[1][(ni * 16 + l15) * 32 + quad * 8];
            sacc[0][ni] = mfma16(qf[0][0], kf0, sacc[0][ni]);
            sacc[0][ni] = mfma16(qf[0][1], kf1, sacc[0][ni]);
            sacc[1][ni] = mfma16(qf[1][0], kf0, sacc[1][ni]);
            sacc[1][ni] = mfma16(qf[1][1], kf1, sacc[1][ni]);
        }

        // mask quirk + exp2 (raw) + local sum
        #pragma unroll
        for (int mi = 0; mi < 2; ++mi)
            #pragma unroll
            for (int ni = 0; ni < 4; ++ni)
                #pragma unroll
                for (int r = 0; r < 4; ++r) {
                    float s = sacc[mi][ni][r];
                    float p_ = (s == 0.f) ? 0.f : __builtin_amdgcn_exp2f(s);
                    sacc[mi][ni][r] = p_;
                    tsum[mi][r] += p_;
                }

        // P through wave-private LDS (stride 36), then O^T += V^T P^T
        #pragma unroll
        for (int kc = 0; kc < 2; ++kc) {
            #pragma unroll
            for (int mi = 0; mi < 2; ++mi)
                #pragma unroll
                for (int nn = 0; nn < 2; ++nn) {
                    const int ni = kc * 2 + nn;
                    #pragma unroll
                    for (int r = 0; r < 4; ++r)
                        lP[w][(mi * 16 + quad * 4 + r) * 36 + nn * 16 + l15] =
                            (bf16_t)sacc[mi][ni][r];
                }
            bf16x8 pf[2];
            #pragma unroll
            for (int mi = 0; mi < 2; ++mi) {
                bf16x4v p0 = *(const bf16x4v*)&lP[w][(mi * 16 + l15) * 36 + quad * 8];
                bf16x4v p1 = *(const bf16x4v*)&lP[w][(mi * 16 + l15) * 36 + quad * 8 + 4];
                #pragma unroll
                for (int j = 0; j < 4; ++j) { pf[mi][j] = p0[j]; pf[mi][4 + j] = p1[j]; }
            }
            #pragma unroll
            for (int nd = 0; nd < 4; ++nd) {
                bf16x8 vf = *(const bf16x8*)&lV[kc][(nd * 16 + l15) * 32 + quad * 8];
                oaccT[0][nd] = mfma16(vf, pf[0], oaccT[0][nd]);   // operand swap -> O^T
                oaccT[1][nd] = mfma16(vf, pf[1], oaccT[1][nd]);
            }
        }
    }

    // row-sum reduction across the 16 key-col lanes (once per block)
    #pragma unroll
    for (int mi = 0; mi < 2; ++mi)
        #pragma unroll
        for (int r = 0; r < 4; ++r) {
            float s_ = tsum[mi][r];
            s_ += __shfl_xor(s_, 1);
            s_ += __shfl_xor(s_, 2);
            s_ += __shfl_xor(s_, 4);
            s_ += __shfl_xor(s_, 8);
            tsum[mi][r] = s_;
        }

    // epilogue: unnormalized O (packed b64 stores) + l
    bf16_t* op = Op + (size_t)sp * 4096 * 512;
    #pragma unroll
    for (int mi = 0; mi < 2; ++mi) {
        const int row = b * 2048 + q0 + w * 32 + mi * 16 + l15;
        #pragma unroll
        for (int nd = 0; nd < 4; ++nd) {
            bf16x4v pk;
            #pragma unroll
            for (int r = 0; r < 4; ++r) pk[r] = (bf16_t)oaccT[mi][nd][r];
            *(bf16x4v*)&op[(size_t)row * 512 + h * 64 + nd * 16 + quad * 4] = pk;
        }
        if (l15 == 0) {
            #pragma unroll
            for (int r = 0; r < 4; ++r) {
                int rr = b * 2048 + q0 + w * 32 + mi * 16 + quad * 4 + r;
                Lb[((size_t)rr * 8 + h) * 4 + sp] = tsum[mi][r];
            }
        }
    }
}

// ---------------------------------------------------------------------------
// LN1: sum 4 attention partials + residual, LayerNorm. 1 wave/row,
// lane owns 8 consecutive columns (all loads/stores 16B coalesced).
// ---------------------------------------------------------------------------
__global__ void lnadd_c(const bf16_t* __restrict__ Op, const float* __restrict__ Lb,
                        const float* __restrict__ hin,
                        const float* __restrict__ g, const float* __restrict__ be,
                        float* __restrict__ Yf, bf16_t* __restrict__ Yb)
{
    const int row = blockIdx.x * 4 + (threadIdx.x >> 6);
    const int lane = threadIdx.x & 63;
    const int c0 = lane * 8;
    const int head = lane >> 3;
    const float4 l4 = *(const float4*)&Lb[((size_t)row * 8 + head) * 4];
    const float linv = 1.f / (l4.x + l4.y + l4.z + l4.w);
    const size_t idx = (size_t)row * 512 + c0;
    bf16x8 o0 = *(const bf16x8*)&Op[idx];
    bf16x8 o1 = *(const bf16x8*)&Op[idx + 2097152];
    bf16x8 o2 = *(const bf16x8*)&Op[idx + 2 * 2097152];
    bf16x8 o3 = *(const bf16x8*)&Op[idx + 3 * 2097152];
    float4 h0 = *(const float4*)&hin[idx];
    float4 h1 = *(const float4*)&hin[idx + 4];
    const float hr[8] = {h0.x, h0.y, h0.z, h0.w, h1.x, h1.y, h1.z, h1.w};
    float v[8]; float s = 0.f;
    #pragma unroll
    for (int j = 0; j < 8; ++j) {
        v[j] = ((float)o0[j] + (float)o1[j] + (float)o2[j] + (float)o3[j]) * linv + hr[j];
        s += v[j];
    }
    #pragma unroll
    for (int off = 32; off >= 1; off >>= 1) s += __shfl_xor(s, off);
    const float mean = s * (1.f / 512.f);
    float vs = 0.f;
    #pragma unroll
    for (int j = 0; j < 8; ++j) { float d = v[j] - mean; vs += d * d; }
    #pragma unroll
    for (int off = 32; off >= 1; off >>= 1) vs += __shfl_xor(vs, off);
    const float inv = rsqrtf(vs * (1.f / 512.f) + 1e-5f);
    float4 g0 = *(const float4*)&g[c0], g1 = *(const float4*)&g[c0 + 4];
    float4 b0 = *(const float4*)&be[c0], b1 = *(const float4*)&be[c0 + 4];
    const float gg[8] = {g0.x, g0.y, g0.z, g0.w, g1.x, g1.y, g1.z, g1.w};
    const float bb[8] = {b0.x, b0.y, b0.z, b0.w, b1.x, b1.y, b1.z, b1.w};
    float y[8]; bf16x8 yb;
    #pragma unroll
    for (int j = 0; j < 8; ++j) {
        y[j] = (v[j] - mean) * inv * gg[j] + bb[j];
        yb[j] = (bf16_t)y[j];
    }
    *(float4*)&Yf[idx]     = make_float4(y[0], y[1], y[2], y[3]);
    *(float4*)&Yf[idx + 4] = make_float4(y[4], y[5], y[6], y[7]);
    *(bf16x8*)&Yb[idx] = yb;
}

// ---------------------------------------------------------------------------
// LN2: sum 4 FFN2 split-K partials + bias + residual, LayerNorm.
// ---------------------------------------------------------------------------
__global__ void lnadd_f(const bf16_t* __restrict__ G, const float* __restrict__ bias,
                        const float* __restrict__ hres, const float* __restrict__ g,
                        const float* __restrict__ be,
                        float* __restrict__ Yf, bf16_t* __restrict__ Yb)
{
    const int row = blockIdx.x * 4 + (threadIdx.x >> 6);
    const int lane = threadIdx.x & 63;
    const int c0 = lane * 8;
    const size_t idx = (size_t)row * 512 + c0;
    bf16x8 o0 = *(const bf16x8*)&G[idx];
    bf16x8 o1 = *(const bf16x8*)&G[idx + 2097152];
    bf16x8 o2 = *(const bf16x8*)&G[idx + 2 * 2097152];
    bf16x8 o3 = *(const bf16x8*)&G[idx + 3 * 2097152];
    float4 h0 = *(const float4*)&hres[idx];
    float4 h1 = *(const float4*)&hres[idx + 4];
    float4 bi0 = *(const float4*)&bias[c0], bi1 = *(const float4*)&bias[c0 + 4];
    const float hr[8] = {h0.x, h0.y, h0.z, h0.w, h1.x, h1.y, h1.z, h1.w};
    const float bs[8] = {bi0.x, bi0.y, bi0.z, bi0.w, bi1.x, bi1.y, bi1.z, bi1.w};
    float v[8]; float s = 0.f;
    #pragma unroll
    for (int j = 0; j < 8; ++j) {
        v[j] = (float)o0[j] + (float)o1[j] + (float)o2[j] + (float)o3[j] + bs[j] + hr[j];
        s += v[j];
    }
    #pragma unroll
    for (int off = 32; off >= 1; off >>= 1) s += __shfl_xor(s, off);
    const float mean = s * (1.f / 512.f);
    float vs = 0.f;
    #pragma unroll
    for (int j = 0; j < 8; ++j) { float d = v[j] - mean; vs += d * d; }
    #pragma unroll
    for (int off = 32; off >= 1; off >>= 1) vs += __shfl_xor(vs, off);
    const float inv = rsqrtf(vs * (1.f / 512.f) + 1e-5f);
    float4 g0 = *(const float4*)&g[c0], g1 = *(const float4*)&g[c0 + 4];
    float4 b0 = *(const float4*)&be[c0], b1 = *(const float4*)&be[c0 + 4];
    const float gg[8] = {g0.x, g0.y, g0.z, g0.w, g1.x, g1.y, g1.z, g1.w};
    const float bb[8] = {b0.x, b0.y, b0.z, b0.w, b1.x, b1.y, b1.z, b1.w};
    float y[8]; bf16x8 yb;
    #pragma unroll
    for (int j = 0; j < 8; ++j) {
        y[j] = (v[j] - mean) * inv * gg[j] + bb[j];
        yb[j] = (bf16_t)y[j];
    }
    *(float4*)&Yf[idx]     = make_float4(y[0], y[1], y[2], y[3]);
    *(float4*)&Yf[idx + 4] = make_float4(y[4], y[5], y[6], y[7]);
    *(bf16x8*)&Yb[idx] = yb;
}

// ---------------------------------------------------------------------------
extern "C" void kernel_launch(void* const* d_in, const int* in_sizes, int n_in,
                              void* d_out, int out_size, void* d_ws, size_t ws_size,
                              hipStream_t stream)
{
    const float* x   = (const float*)d_in[0];
    const float* Wq  = (const float*)d_in[1];
    const float* bq  = (const float*)d_in[2];
    const float* Wk  = (const float*)d_in[3];
    const float* bk  = (const float*)d_in[4];
    const float* Wv  = (const float*)d_in[5];
    const float* bv  = (const float*)d_in[6];
    const float* W1  = (const float*)d_in[7];
    const float* b1  = (const float*)d_in[8];
    const float* W2  = (const float*)d_in[9];
    const float* b2  = (const float*)d_in[10];
    const float* g1  = (const float*)d_in[11];
    const float* be1 = (const float*)d_in[12];
    const float* g2  = (const float*)d_in[13];
    const float* be2 = (const float*)d_in[14];

    char* p = (char*)d_ws;
    auto carve = [&](size_t bytes) { char* r = p; p += (bytes + 255) & ~(size_t)255; return r; };
    bf16_t* wQKV = (bf16_t*)carve(4UL * 1536 * 512 * 2);
    bf16_t* wW1t = (bf16_t*)carve(4UL * 2048 * 512 * 2);
    bf16_t* wW2t = (bf16_t*)carve(4UL * 512 * 2048 * 2);
    bf16_t* hbf  = (bf16_t*)carve(4096UL * 512 * 2);       // bf16 of current h
    bf16_t* h2b  = (bf16_t*)carve(4096UL * 512 * 2);       // bf16 of LN1 out
    bf16_t* Fb   = (bf16_t*)carve(4096UL * 2048 * 2);      // FFN1 out; Q/K/V alias
    bf16_t* R2   = (bf16_t*)carve(4UL * 4096 * 512 * 2);   // attn / FFN2 partials
    float*  Lbuf = (float*)carve(4096UL * 8 * 4 * 4);
    float*  h2f  = (float*)carve(4096UL * 512 * 4);        // LN1 out fp32
    float*  hf   = (float*)carve(4096UL * 512 * 4);        // h master fp32
    bf16_t* Qb  = Fb;
    bf16_t* Kb  = Fb + 4096UL * 512;
    bf16_t* Vtb = Fb + 2UL * 4096 * 512;                   // [b][h][64][2048]

    wconv_kernel<<<dim3(704, 4), 256, 0, stream>>>(Wq, Wk, Wv, W1, W2, wQKV, wW1t, wW2t);
    f2b_kernel<<<dim3(1024), 256, 0, stream>>>(x, hbf, 4096 * 512);

    const float* hin = x;
    for (int l = 0; l < 4; ++l) {
        gemm_kernel<2, false><<<dim3(12, 32, 1), 256, 0, stream>>>(
            hbf, wQKV + (size_t)l * 1536 * 512,
            bq + l * 512, bk + l * 512, bv + l * 512,
            Qb, Kb, Vtb, 1536, 512, 512);
        attn_kernel<<<dim3(64, 16), 256, 0, stream>>>(Qb, Kb, Vtb, R2, Lbuf);
        lnadd_c<<<dim3(1024), 256, 0, stream>>>(R2, Lbuf, hin,
                                                g1 + l * 512, be1 + l * 512, h2f, h2b);
        gemm_kernel<1, true><<<dim3(16, 32, 1), 256, 0, stream>>>(
            h2b, wW1t + (size_t)l * 2048 * 512,
            b1 + l * 2048, nullptr, nullptr,
            Fb, nullptr, nullptr, 2048, 512, 512);
        gemm_kernel<3, false><<<dim3(4, 32, 4), 256, 0, stream>>>(
            Fb, wW2t + (size_t)l * 512 * 2048,
            nullptr, nullptr, nullptr,
            R2, nullptr, nullptr, 512, 2048, 512);
        float* yout = (l == 3) ? (float*)d_out : hf;
        lnadd_f<<<dim3(1024), 256, 0, stream>>>(R2, b2 + l * 512, h2f,
                                                g2 + l * 512, be2 + l * 512, yout, hbf);
        hin = hf;
    }
    (void)in_sizes; (void)n_in; (void)out_size; (void)ws_size;
}